// Round 1
// baseline (549.369 us; speedup 1.0000x reference)
//
#include <hip/hip_runtime.h>
#include <hip/hip_bf16.h>

#define B_ 32
#define N_ 2048
#define D_ 512
#define KC_ 64
#define KG_ 80
#define M_ (B_*N_)   // 65536

// ---------------- K1: a = x @ clusters  + column sums S1,S2 ----------------
// grid 512 (128 rows each), block 256. Tile 128x80, BK=32.
// thread: rg=t>>4 (row group), c5=t&15 (col group); 8 rows x 5 cols per thread.
__global__ __launch_bounds__(256) void k1_proj(
    const float* __restrict__ x, const float* __restrict__ cl,
    float* __restrict__ a, float* __restrict__ S1, float* __restrict__ S2)
{
  __shared__ float xs[128*36];   // stride 36 keeps 16B align + conflict-free
  __shared__ float cs[80*36];    // transposed clusters tile [col][kk]
  __shared__ float ls1[KG_], ls2[KG_];
  const int t = threadIdx.x;
  const int row0 = blockIdx.x * 128;
  const int rg = t >> 4;
  const int c5 = t & 15;
  float acc[8][5];
#pragma unroll
  for (int i=0;i<8;i++)
#pragma unroll
    for (int j=0;j<5;j++) acc[i][j]=0.f;

  for (int k0=0;k0<D_;k0+=32){
#pragma unroll
    for (int l=0;l<4;l++){
      int idx = t + 256*l;            // 0..1023 = 128 rows * 8 segs
      int r = idx>>3, seg = idx&7;
      *(float4*)&xs[r*36+seg*4] = *(const float4*)&x[(size_t)(row0+r)*D_ + k0 + seg*4];
    }
#pragma unroll
    for (int l=0;l<10;l++){
      int idx = t + 256*l;            // 0..2559 = 32 kk * 80 col
      int kk = idx/80, col = idx - kk*80;
      cs[col*36+kk] = cl[(size_t)(k0+kk)*KG_ + col];
    }
    __syncthreads();
#pragma unroll
    for (int q=0;q<8;q++){
      float4 xv[8], cv[5];
#pragma unroll
      for (int i=0;i<8;i++) xv[i] = *(float4*)&xs[(rg+16*i)*36 + q*4];
#pragma unroll
      for (int j=0;j<5;j++) cv[j] = *(float4*)&cs[(c5+16*j)*36 + q*4];
#pragma unroll
      for (int i=0;i<8;i++)
#pragma unroll
        for (int j=0;j<5;j++)
          acc[i][j] += xv[i].x*cv[j].x + xv[i].y*cv[j].y
                     + xv[i].z*cv[j].z + xv[i].w*cv[j].w;
    }
    __syncthreads();
  }
  if (t < KG_){ ls1[t]=0.f; ls2[t]=0.f; }
  __syncthreads();
  float p1[5]={0,0,0,0,0}, p2[5]={0,0,0,0,0};
#pragma unroll
  for (int i=0;i<8;i++){
    int r = rg + 16*i;
#pragma unroll
    for (int j=0;j<5;j++){
      int col = c5 + 16*j;
      float v = acc[i][j];
      a[(size_t)(row0+r)*KG_ + col] = v;
      p1[j] += v; p2[j] += v*v;
    }
  }
#pragma unroll
  for (int j=0;j<5;j++){
    atomicAdd(&ls1[c5+16*j], p1[j]);
    atomicAdd(&ls2[c5+16*j], p2[j]);
  }
  __syncthreads();
  if (t < KG_){ atomicAdd(&S1[t], ls1[t]); atomicAdd(&S2[t], ls2[t]); }
}

// ---------------- K2: BN finalize -> scale/shift ----------------
__global__ void k2_bn(const float* __restrict__ S1, const float* __restrict__ S2,
                      const float* __restrict__ gamma, const float* __restrict__ beta,
                      float* __restrict__ scale, float* __restrict__ shift)
{
  int t = threadIdx.x;
  if (t < KG_){
    const float invM = 1.0f / (float)M_;
    float mean = S1[t] * invM;
    float var  = S2[t] * invM - mean*mean;
    float sc = gamma[t] * rsqrtf(var + 1e-5f);
    scale[t] = sc;
    shift[t] = beta[t] - mean*sc;
  }
}

// ---------------- K3: BN affine + softmax (in-place p into a) + a_sum ------
// grid 1024 (64 rows each), block 256 (4 threads per row).
__global__ __launch_bounds__(256) void k3_softmax(
    float* __restrict__ a, const float* __restrict__ scale,
    const float* __restrict__ shift, float* __restrict__ asum)
{
  __shared__ float as[64*84];
  __shared__ float sc[KG_], sh[KG_];
  __shared__ float lsum[KC_];
  const int t = threadIdx.x;
  const int row0 = blockIdx.x * 64;
  if (t < KG_){ sc[t]=scale[t]; sh[t]=shift[t]; }
  if (t < KC_) lsum[t]=0.f;
  __syncthreads();
#pragma unroll
  for (int l=0;l<20;l++){
    int idx = t + 256*l;              // 0..5119 = 64 rows * 80 cols
    int r = idx/80, col = idx - r*80;
    float v = a[(size_t)(row0+r)*KG_ + col];
    as[r*84+col] = v*sc[col] + sh[col];
  }
  __syncthreads();
  const int rt = t >> 2;   // row in block
  const int g  = t & 3;    // 4-thread group per row; cols g+4c
  float m = -1e30f;
#pragma unroll
  for (int c=0;c<20;c++) m = fmaxf(m, as[rt*84 + g + 4*c]);
  m = fmaxf(m, __shfl_xor(m,1));
  m = fmaxf(m, __shfl_xor(m,2));
  float e[20]; float s = 0.f;
#pragma unroll
  for (int c=0;c<20;c++){ float v = __expf(as[rt*84 + g + 4*c] - m); e[c]=v; s+=v; }
  s += __shfl_xor(s,1);
  s += __shfl_xor(s,2);
  const float inv = 1.f/s;
#pragma unroll
  for (int c=0;c<16;c++){             // kept cols < 64
    int col = g + 4*c;
    float pv = e[c]*inv;
    a[(size_t)(row0+rt)*KG_ + col] = pv;   // in-place p
    float su = pv;                     // reduce over the 16 rows in this wave
    su += __shfl_xor(su,4);  su += __shfl_xor(su,8);
    su += __shfl_xor(su,16); su += __shfl_xor(su,32);
    if ((t&63) < 4) atomicAdd(&lsum[col], su);
  }
  __syncthreads();
  if (t < KC_) atomicAdd(&asum[(blockIdx.x>>5)*KC_ + t], lsum[t]);
}

// ---------------- K4: vlad partials vp[ns][b][d][k] = x[b]^T @ p[b] --------
// grid 512 = 32 b * 2 dtiles(256 d) * 8 nsplits(256 n). block 256.
// micro-tile 8d x 8k per thread (kg=t&7, dg=t>>3).
__global__ __launch_bounds__(256) void k4_vlad(
    const float* __restrict__ x, const float* __restrict__ p, float* __restrict__ vp)
{
  __shared__ float xs[32*256];
  __shared__ float ps[32*64];
  const int t = threadIdx.x;
  const int blk = blockIdx.x;
  const int ns = blk & 7;
  const int dt = (blk>>3) & 1;
  const int b  = blk>>4;
  const int kg = t & 7;
  const int dg = t >> 3;
  float4 acc[8][2];
#pragma unroll
  for (int i=0;i<8;i++){ acc[i][0]=make_float4(0,0,0,0); acc[i][1]=make_float4(0,0,0,0); }
  const int nbase = ns*256;
  for (int n0=0;n0<256;n0+=32){
#pragma unroll
    for (int l=0;l<8;l++){
      int idx = t + 256*l;            // 32 rows * 64 float4
      int nn = idx>>6, seg = idx&63;
      size_t grow = (size_t)b*N_ + nbase + n0 + nn;
      *(float4*)&xs[nn*256+seg*4] = *(const float4*)&x[grow*D_ + dt*256 + seg*4];
    }
#pragma unroll
    for (int l=0;l<2;l++){
      int idx = t + 256*l;            // 32 rows * 16 float4
      int nn = idx>>4, seg = idx&15;
      size_t grow = (size_t)b*N_ + nbase + n0 + nn;
      *(float4*)&ps[nn*64+seg*4] = *(const float4*)&p[grow*KG_ + seg*4];
    }
    __syncthreads();
#pragma unroll
    for (int nn=0;nn<32;nn++){
      float4 xv0 = *(float4*)&xs[nn*256 + dg*8];
      float4 xv1 = *(float4*)&xs[nn*256 + dg*8 + 4];
      float4 pv0 = *(float4*)&ps[nn*64 + kg*8];
      float4 pv1 = *(float4*)&ps[nn*64 + kg*8 + 4];
      float xd[8] = {xv0.x,xv0.y,xv0.z,xv0.w,xv1.x,xv1.y,xv1.z,xv1.w};
#pragma unroll
      for (int i=0;i<8;i++){
        acc[i][0].x += xd[i]*pv0.x; acc[i][0].y += xd[i]*pv0.y;
        acc[i][0].z += xd[i]*pv0.z; acc[i][0].w += xd[i]*pv0.w;
        acc[i][1].x += xd[i]*pv1.x; acc[i][1].y += xd[i]*pv1.y;
        acc[i][1].z += xd[i]*pv1.z; acc[i][1].w += xd[i]*pv1.w;
      }
    }
    __syncthreads();
  }
#pragma unroll
  for (int i=0;i<8;i++){
    size_t d = (size_t)dt*256 + dg*8 + i;
    size_t base = (((size_t)ns*B_ + b)*D_ + d)*KC_ + kg*8;
    *(float4*)&vp[base]   = acc[i][0];
    *(float4*)&vp[base+4] = acc[i][1];
  }
}

// ---------------- K5: combine splits, subtract, intra+global L2 norm -------
// grid 32 (one b each), block 1024. k=t&63, dg=t>>6, d=dg+16*s.
__global__ __launch_bounds__(1024) void k5_norm(
    const float* __restrict__ vp, const float* __restrict__ c2,
    const float* __restrict__ asum, float* __restrict__ out)
{
  __shared__ float part[16][64];
  __shared__ float invd[64];
  __shared__ float gi_s;
  const int b = blockIdx.x;
  const int t = threadIdx.x;
  const int k = t & 63, dg = t >> 6;
  const float av = asum[b*KC_ + k];
  const size_t stride = (size_t)B_*D_*KC_;
  float v[32];
  float ss = 0.f;
#pragma unroll
  for (int s=0;s<32;s++){
    int d = dg + 16*s;
    size_t idx = ((size_t)b*D_ + d)*KC_ + k;
    float vv = 0.f;
#pragma unroll
    for (int nsp=0;nsp<8;nsp++) vv += vp[idx + (size_t)nsp*stride];
    vv -= c2[d*KC_ + k]*av;
    v[s] = vv;
    ss += vv*vv;
  }
  part[dg][k] = ss;
  __syncthreads();
  if (t < 64){
    float n2 = 0.f;
#pragma unroll
    for (int i=0;i<16;i++) n2 += part[i][t];
    float nn = sqrtf(n2);
    float denom = fmaxf(nn, 1e-12f);
    invd[t] = 1.f/denom;
    float ratio = nn/denom;
    float r2 = ratio*ratio;
#pragma unroll
    for (int mm=1;mm<64;mm<<=1) r2 += __shfl_xor(r2, mm);
    if (t==0){
      float g = sqrtf(r2);
      gi_s = 1.f/fmaxf(g, 1e-12f);
    }
  }
  __syncthreads();
  const float gi = gi_s;
  const float ik = invd[k];
#pragma unroll
  for (int s=0;s<32;s++){
    int d = dg + 16*s;
    out[(size_t)b*(D_*KC_) + (size_t)d*KC_ + k] = v[s]*ik*gi;
  }
}

extern "C" void kernel_launch(void* const* d_in, const int* in_sizes, int n_in,
                              void* d_out, int out_size, void* d_ws, size_t ws_size,
                              hipStream_t stream)
{
  const float* x     = (const float*)d_in[0];
  const float* cl    = (const float*)d_in[1];
  const float* c2    = (const float*)d_in[2];
  const float* gamma = (const float*)d_in[3];
  const float* beta  = (const float*)d_in[4];
  float* out = (float*)d_out;
  float* ws  = (float*)d_ws;

  // ws layout (floats): S1[80] S2[80] scale[80] shift[80] asum[2048] pad..4096
  //  a/p [M*80] @4096 (softmax writes p in place, stride 80)
  //  vp  [8 * B*D*KC] after a  -> total ~54.6 MB
  float* S1    = ws;
  float* S2    = ws + 80;
  float* scale = ws + 160;
  float* shift = ws + 240;
  float* asum  = ws + 320;
  float* a     = ws + 4096;
  float* vp    = a + (size_t)M_*KG_;

  hipMemsetAsync(ws, 0, 2368*sizeof(float), stream);
  k1_proj   <<<512, 256, 0, stream>>>(x, cl, a, S1, S2);
  k2_bn     <<<1, 128, 0, stream>>>(S1, S2, gamma, beta, scale, shift);
  k3_softmax<<<1024, 256, 0, stream>>>(a, scale, shift, asum);
  k4_vlad   <<<512, 256, 0, stream>>>(x, a, vp);
  k5_norm   <<<32, 1024, 0, stream>>>(vp, c2, asum, out);
}

// Round 2
// 276.211 us; speedup vs baseline: 1.9889x; 1.9889x over previous
//
#include <hip/hip_runtime.h>
#include <hip/hip_bf16.h>

#define B_ 32
#define N_ 2048
#define D_ 512
#define KC_ 64
#define KG_ 80
#define M_ (B_*N_)   // 65536

typedef __attribute__((ext_vector_type(8))) short short8;
typedef __attribute__((ext_vector_type(4))) float f32x4;

// fp32 -> bf16 round-to-nearest-even, bit trick (finite inputs only)
__device__ __forceinline__ unsigned short bf_rn(float f){
  unsigned int u = __float_as_uint(f);
  unsigned int r = u + 0x7FFFu + ((u >> 16) & 1u);
  return (unsigned short)(r >> 16);
}
__device__ __forceinline__ float bf_up(unsigned short h){
  return __uint_as_float(((unsigned int)h) << 16);
}
// 8 fp32 -> hi/lo bf16 frags
__device__ __forceinline__ void cvt8(const float* v, short8& hi, short8& lo){
#pragma unroll
  for (int i=0;i<8;i++){
    unsigned short h = bf_rn(v[i]);
    float rem = v[i] - bf_up(h);
    hi[i] = (short)h;
    lo[i] = (short)bf_rn(rem);
  }
}

// ---------------- K0: clusters -> fragment-ordered bf16 hi/lo --------------
// Bf layout: frag f = (c*5 + j)*2 + hl  (c: k-chunk of 32, j: col-tile, hl)
// element: Bf[f*512 + lane*8 + jj] = bf16 of cl[(c*32 + (lane>>4)*8 + jj)*80 + j*16 + (lane&15)]
__global__ __launch_bounds__(256) void k0_prep(const float* __restrict__ cl,
                                               unsigned short* __restrict__ Bf)
{
  int tid = blockIdx.x*256 + threadIdx.x;     // 40*256 = 10240
  int l  = tid & 63;
  int hl = (tid >> 6) & 1;
  int j  = (tid >> 7) % 5;
  int c  = tid / 640;
  int kk  = c*32 + (l>>4)*8;
  int col = j*16 + (l&15);
  unsigned short o[8];
#pragma unroll
  for (int jj=0;jj<8;jj++){
    float v = cl[(size_t)(kk+jj)*KG_ + col];
    unsigned short h = bf_rn(v);
    if (hl == 0) o[jj] = h;
    else         o[jj] = bf_rn(v - bf_up(h));
  }
#pragma unroll
  for (int jj=0;jj<8;jj++) Bf[(size_t)tid*8 + jj] = o[jj];
}

// ---------------- K1: a = x @ clusters (MFMA, split-bf16) + col sums -------
// grid 512 (128 rows), block 256 = 4 waves; wave: 32 rows (2 tiles) x 80 cols.
// No LDS in main loop; A frags loaded straight from global, B frags from Bf.
__global__ __launch_bounds__(256) void k1_proj(
    const float* __restrict__ x, const unsigned short* __restrict__ Bf,
    float* __restrict__ a, float* __restrict__ S1, float* __restrict__ S2)
{
  __shared__ float ls1[KG_], ls2[KG_];
  const int t = threadIdx.x;
  const int w = t >> 6, lane = t & 63;
  const int m = lane & 15, q = lane >> 4;
  const int row0 = blockIdx.x*128 + w*32;
  if (t < KG_){ ls1[t]=0.f; ls2[t]=0.f; }

  const float* xr0 = x + (size_t)(row0 + m)*D_ + q*8;
  const float* xr1 = xr0 + (size_t)16*D_;

  f32x4 acc[2][5];
#pragma unroll
  for (int rt=0;rt<2;rt++)
#pragma unroll
    for (int j=0;j<5;j++) acc[rt][j] = (f32x4){0.f,0.f,0.f,0.f};

  for (int c=0;c<16;c++){
    float v0[8], v1[8];
    *(float4*)&v0[0] = *(const float4*)(xr0 + c*32);
    *(float4*)&v0[4] = *(const float4*)(xr0 + c*32 + 4);
    *(float4*)&v1[0] = *(const float4*)(xr1 + c*32);
    *(float4*)&v1[4] = *(const float4*)(xr1 + c*32 + 4);
    short8 ah0, al0, ah1, al1;
    cvt8(v0, ah0, al0);
    cvt8(v1, ah1, al1);
    const unsigned short* bp = Bf + (size_t)(c*5)*1024 + lane*8;
#pragma unroll
    for (int j=0;j<5;j++){
      short8 bhi = *(const short8*)(bp + (size_t)j*1024);
      short8 blo = *(const short8*)(bp + (size_t)j*1024 + 512);
      acc[0][j] = __builtin_amdgcn_mfma_f32_16x16x32_bf16(ah0, bhi, acc[0][j], 0,0,0);
      acc[0][j] = __builtin_amdgcn_mfma_f32_16x16x32_bf16(al0, bhi, acc[0][j], 0,0,0);
      acc[0][j] = __builtin_amdgcn_mfma_f32_16x16x32_bf16(ah0, blo, acc[0][j], 0,0,0);
      acc[1][j] = __builtin_amdgcn_mfma_f32_16x16x32_bf16(ah1, bhi, acc[1][j], 0,0,0);
      acc[1][j] = __builtin_amdgcn_mfma_f32_16x16x32_bf16(al1, bhi, acc[1][j], 0,0,0);
      acc[1][j] = __builtin_amdgcn_mfma_f32_16x16x32_bf16(ah1, blo, acc[1][j], 0,0,0);
    }
  }

  // epilogue: store a + fused column sums
  float s1v[5] = {0,0,0,0,0}, s2v[5] = {0,0,0,0,0};
#pragma unroll
  for (int rt=0;rt<2;rt++){
#pragma unroll
    for (int j=0;j<5;j++){
      f32x4 v = acc[rt][j];
      size_t base = (size_t)(row0 + rt*16 + q*4)*KG_ + j*16 + m;
      a[base]        = v[0];
      a[base+KG_]    = v[1];
      a[base+2*KG_]  = v[2];
      a[base+3*KG_]  = v[3];
      s1v[j] += v[0]+v[1]+v[2]+v[3];
      s2v[j] += v[0]*v[0]+v[1]*v[1]+v[2]*v[2]+v[3]*v[3];
    }
  }
#pragma unroll
  for (int j=0;j<5;j++){
    float s1 = s1v[j], s2 = s2v[j];
    s1 += __shfl_xor(s1,16); s1 += __shfl_xor(s1,32);
    s2 += __shfl_xor(s2,16); s2 += __shfl_xor(s2,32);
    if (q == 0){
      atomicAdd(&ls1[j*16+m], s1);
      atomicAdd(&ls2[j*16+m], s2);
    }
  }
  __syncthreads();
  if (t < KG_){ atomicAdd(&S1[t], ls1[t]); atomicAdd(&S2[t], ls2[t]); }
}

// ---------------- K2: BN finalize -> scale/shift ----------------
__global__ void k2_bn(const float* __restrict__ S1, const float* __restrict__ S2,
                      const float* __restrict__ gamma, const float* __restrict__ beta,
                      float* __restrict__ scale, float* __restrict__ shift)
{
  int t = threadIdx.x;
  if (t < KG_){
    const float invM = 1.0f / (float)M_;
    float mean = S1[t] * invM;
    float var  = S2[t] * invM - mean*mean;
    float sc = gamma[t] * rsqrtf(var + 1e-5f);
    scale[t] = sc;
    shift[t] = beta[t] - mean*sc;
  }
}

// ---------------- K3: BN affine + softmax (in-place p into a) + a_sum ------
__global__ __launch_bounds__(256) void k3_softmax(
    float* __restrict__ a, const float* __restrict__ scale,
    const float* __restrict__ shift, float* __restrict__ asum)
{
  __shared__ float as[64*84];
  __shared__ float sc[KG_], sh[KG_];
  __shared__ float lsum[KC_];
  const int t = threadIdx.x;
  const int row0 = blockIdx.x * 64;
  if (t < KG_){ sc[t]=scale[t]; sh[t]=shift[t]; }
  if (t < KC_) lsum[t]=0.f;
  __syncthreads();
#pragma unroll
  for (int l=0;l<20;l++){
    int idx = t + 256*l;
    int r = idx/80, col = idx - r*80;
    float v = a[(size_t)(row0+r)*KG_ + col];
    as[r*84+col] = v*sc[col] + sh[col];
  }
  __syncthreads();
  const int rt = t >> 2;
  const int g  = t & 3;
  float m = -1e30f;
#pragma unroll
  for (int c=0;c<20;c++) m = fmaxf(m, as[rt*84 + g + 4*c]);
  m = fmaxf(m, __shfl_xor(m,1));
  m = fmaxf(m, __shfl_xor(m,2));
  float e[20]; float s = 0.f;
#pragma unroll
  for (int c=0;c<20;c++){ float v = __expf(as[rt*84 + g + 4*c] - m); e[c]=v; s+=v; }
  s += __shfl_xor(s,1);
  s += __shfl_xor(s,2);
  const float inv = 1.f/s;
#pragma unroll
  for (int c=0;c<16;c++){
    int col = g + 4*c;
    float pv = e[c]*inv;
    a[(size_t)(row0+rt)*KG_ + col] = pv;
    float su = pv;
    su += __shfl_xor(su,4);  su += __shfl_xor(su,8);
    su += __shfl_xor(su,16); su += __shfl_xor(su,32);
    if ((t&63) < 4) atomicAdd(&lsum[col], su);
  }
  __syncthreads();
  if (t < KC_) atomicAdd(&asum[(blockIdx.x>>5)*KC_ + t], lsum[t]);
}

// ---------------- K4: vlad partials (MFMA, split-bf16) ---------------------
// grid 1024 = 32 b * 8 dtiles(64) * 4 nsplits(512). block 256 = 4 waves.
// Block: [64 d x 64 kc], K over 512 n in chunks of 32, LDS-transposed frags.
__global__ __launch_bounds__(256) void k4_vlad(
    const float* __restrict__ x, const float* __restrict__ p, float* __restrict__ vp)
{
  __shared__ unsigned short xh[64*40], xl[64*40];
  __shared__ unsigned short ph[64*40], pl[64*40];
  const int t = threadIdx.x;
  const int blk = blockIdx.x;
  const int ns = blk & 3;
  const int dt = (blk >> 2) & 7;
  const int b  = blk >> 5;
  const int w = t >> 6, lane = t & 63;
  const int m = lane & 15, q = lane >> 4;
  const int d0 = dt*64;
  const int nbase = ns*512;
  const int dloc = t & 63, ng = t >> 6;

  f32x4 acc[4];
#pragma unroll
  for (int j=0;j<4;j++) acc[j] = (f32x4){0.f,0.f,0.f,0.f};

  for (int n0=0;n0<512;n0+=32){
    // stage x[b][n0..n0+31][d0+dloc] -> xh/xl[dloc][n], 8 n per thread
    {
      float v[8];
      const float* xp = x + ((size_t)b*N_ + nbase + n0 + ng*8)*D_ + d0 + dloc;
#pragma unroll
      for (int jj=0;jj<8;jj++) v[jj] = xp[(size_t)jj*D_];
      short8 hi, lo; cvt8(v, hi, lo);
      *(short8*)&xh[dloc*40 + ng*8] = hi;
      *(short8*)&xl[dloc*40 + ng*8] = lo;
    }
    // stage p[b][n0..n0+31][dloc(<64)] -> ph/pl[kc][n]
    {
      float v[8];
      const float* pp = p + ((size_t)b*N_ + nbase + n0 + ng*8)*KG_ + dloc;
#pragma unroll
      for (int jj=0;jj<8;jj++) v[jj] = pp[(size_t)jj*KG_];
      short8 hi, lo; cvt8(v, hi, lo);
      *(short8*)&ph[dloc*40 + ng*8] = hi;
      *(short8*)&pl[dloc*40 + ng*8] = lo;
    }
    __syncthreads();
    short8 ahi = *(const short8*)&xh[(w*16+m)*40 + q*8];
    short8 alo = *(const short8*)&xl[(w*16+m)*40 + q*8];
#pragma unroll
    for (int j=0;j<4;j++){
      short8 bhi = *(const short8*)&ph[(j*16+m)*40 + q*8];
      short8 blo = *(const short8*)&pl[(j*16+m)*40 + q*8];
      acc[j] = __builtin_amdgcn_mfma_f32_16x16x32_bf16(ahi, bhi, acc[j], 0,0,0);
      acc[j] = __builtin_amdgcn_mfma_f32_16x16x32_bf16(alo, bhi, acc[j], 0,0,0);
      acc[j] = __builtin_amdgcn_mfma_f32_16x16x32_bf16(ahi, blo, acc[j], 0,0,0);
    }
    __syncthreads();
  }
#pragma unroll
  for (int j=0;j<4;j++){
    f32x4 v = acc[j];
    size_t base = (((size_t)ns*B_ + b)*D_ + d0 + w*16 + q*4)*KC_ + j*16 + m;
    vp[base]         = v[0];
    vp[base +   KC_] = v[1];
    vp[base + 2*KC_] = v[2];
    vp[base + 3*KC_] = v[3];
  }
}

// ---------------- K5: combine 4 splits, subtract, intra+global L2 norm -----
__global__ __launch_bounds__(1024) void k5_norm(
    const float* __restrict__ vp, const float* __restrict__ c2,
    const float* __restrict__ asum, float* __restrict__ out)
{
  __shared__ float part[16][64];
  __shared__ float invd[64];
  __shared__ float gi_s;
  const int b = blockIdx.x;
  const int t = threadIdx.x;
  const int k = t & 63, dg = t >> 6;
  const float av = asum[b*KC_ + k];
  const size_t stride = (size_t)B_*D_*KC_;
  float v[32];
  float ss = 0.f;
#pragma unroll
  for (int s=0;s<32;s++){
    int d = dg + 16*s;
    size_t idx = ((size_t)b*D_ + d)*KC_ + k;
    float vv = 0.f;
#pragma unroll
    for (int nsp=0;nsp<4;nsp++) vv += vp[idx + (size_t)nsp*stride];
    vv -= c2[d*KC_ + k]*av;
    v[s] = vv;
    ss += vv*vv;
  }
  part[dg][k] = ss;
  __syncthreads();
  if (t < 64){
    float n2 = 0.f;
#pragma unroll
    for (int i=0;i<16;i++) n2 += part[i][t];
    float nn = sqrtf(n2);
    float denom = fmaxf(nn, 1e-12f);
    invd[t] = 1.f/denom;
    float ratio = nn/denom;
    float r2 = ratio*ratio;
#pragma unroll
    for (int mm=1;mm<64;mm<<=1) r2 += __shfl_xor(r2, mm);
    if (t==0){
      float g = sqrtf(r2);
      gi_s = 1.f/fmaxf(g, 1e-12f);
    }
  }
  __syncthreads();
  const float gi = gi_s;
  const float ik = invd[k];
#pragma unroll
  for (int s=0;s<32;s++){
    int d = dg + 16*s;
    out[(size_t)b*(D_*KC_) + (size_t)d*KC_ + k] = v[s]*ik*gi;
  }
}

extern "C" void kernel_launch(void* const* d_in, const int* in_sizes, int n_in,
                              void* d_out, int out_size, void* d_ws, size_t ws_size,
                              hipStream_t stream)
{
  const float* x     = (const float*)d_in[0];
  const float* cl    = (const float*)d_in[1];
  const float* c2    = (const float*)d_in[2];
  const float* gamma = (const float*)d_in[3];
  const float* beta  = (const float*)d_in[4];
  float* out = (float*)d_out;
  float* ws  = (float*)d_ws;

  // ws (floats): S1[80] S2[80] scale[80] shift[80] asum[2048] pad->4096
  //   Bf (ushort 81920 = 40960 floats) @4096
  //   a [M*80] @45056 ; vp [4*B*D*KC] after a
  float* S1    = ws;
  float* S2    = ws + 80;
  float* scale = ws + 160;
  float* shift = ws + 240;
  float* asum  = ws + 320;
  unsigned short* Bf = (unsigned short*)(ws + 4096);
  float* a     = ws + 45056;
  float* vp    = a + (size_t)M_*KG_;

  hipMemsetAsync(ws, 0, 2368*sizeof(float), stream);
  k0_prep   <<<40,   256, 0, stream>>>(cl, Bf);
  k1_proj   <<<512,  256, 0, stream>>>(x, Bf, a, S1, S2);
  k2_bn     <<<1,    128, 0, stream>>>(S1, S2, gamma, beta, scale, shift);
  k3_softmax<<<1024, 256, 0, stream>>>(a, scale, shift, asum);
  k4_vlad   <<<1024, 256, 0, stream>>>(x, a, vp);
  k5_norm   <<<32,  1024, 0, stream>>>(vp, c2, asum, out);
}